// Round 3
// baseline (2139.759 us; speedup 1.0000x reference)
//
#include <hip/hip_runtime.h>

// DPP helpers (builtin path: direction probe + final reduce only)
#define ROTI(v, CTRL) __builtin_amdgcn_update_dpp(0, (v), (CTRL), 0xF, 0xF, true)
#define ROTF(x, CTRL) __int_as_float(__builtin_amdgcn_update_dpp(0, __float_as_int(x), (CTRL), 0xF, 0xF, true))

constexpr int T_LEN = 8192;
constexpr int BATCH = 256;
constexpr int HID   = 16;
constexpr int G     = 4;    // independent batch streams per lane (ILP)

// Fused step-core (identical schedule to round 2, which passed):
// 16x16 matvec via v_fmac_f32_dpp/v_mul_f32_dpp on pre-rotated weight rows,
// with the PREVIOUS step's output-projection reduce (v_add_f32_dpp tree)
// interleaved. Hazard discipline: s_nop 1 at head; >=3-inst spacing between
// any write and DPP-read of the same VGPR inside the block.
#define MATVEC(a0_, a1_, a2_, a3_, p_, h_)                                              \
  asm("s_nop 1\n\t"                                                                     \
      "v_fmac_f32 %[a0], %[h], %[w0]\n\t"                                               \
      "v_mul_f32_dpp %[a1], %[h], %[w4] row_ror:4 row_mask:0xf bank_mask:0xf\n\t"       \
      "v_mul_f32_dpp %[a2], %[h], %[w8] row_ror:8 row_mask:0xf bank_mask:0xf\n\t"       \
      "v_mul_f32_dpp %[a3], %[h], %[w12] row_ror:12 row_mask:0xf bank_mask:0xf\n\t"     \
      "v_add_f32_dpp %[p], %[p], %[p] row_ror:8 row_mask:0xf bank_mask:0xf\n\t"         \
      "v_fmac_f32_dpp %[a0], %[h], %[w1] row_ror:1 row_mask:0xf bank_mask:0xf\n\t"      \
      "v_fmac_f32_dpp %[a1], %[h], %[w5] row_ror:5 row_mask:0xf bank_mask:0xf\n\t"      \
      "v_fmac_f32_dpp %[a2], %[h], %[w9] row_ror:9 row_mask:0xf bank_mask:0xf\n\t"      \
      "v_add_f32_dpp %[p], %[p], %[p] row_ror:4 row_mask:0xf bank_mask:0xf\n\t"         \
      "v_fmac_f32_dpp %[a3], %[h], %[w13] row_ror:13 row_mask:0xf bank_mask:0xf\n\t"    \
      "v_fmac_f32_dpp %[a0], %[h], %[w2] row_ror:2 row_mask:0xf bank_mask:0xf\n\t"      \
      "v_fmac_f32_dpp %[a1], %[h], %[w6] row_ror:6 row_mask:0xf bank_mask:0xf\n\t"      \
      "v_add_f32_dpp %[p], %[p], %[p] row_ror:2 row_mask:0xf bank_mask:0xf\n\t"         \
      "v_fmac_f32_dpp %[a2], %[h], %[w10] row_ror:10 row_mask:0xf bank_mask:0xf\n\t"    \
      "v_fmac_f32_dpp %[a3], %[h], %[w14] row_ror:14 row_mask:0xf bank_mask:0xf\n\t"    \
      "v_fmac_f32_dpp %[a0], %[h], %[w3] row_ror:3 row_mask:0xf bank_mask:0xf\n\t"      \
      "v_add_f32_dpp %[p], %[p], %[p] row_ror:1 row_mask:0xf bank_mask:0xf\n\t"         \
      "v_fmac_f32_dpp %[a1], %[h], %[w7] row_ror:7 row_mask:0xf bank_mask:0xf\n\t"      \
      "v_fmac_f32_dpp %[a2], %[h], %[w11] row_ror:11 row_mask:0xf bank_mask:0xf\n\t"    \
      "v_fmac_f32_dpp %[a3], %[h], %[w15] row_ror:15 row_mask:0xf bank_mask:0xf\n\t"    \
      : [a0]"+v"(a0_), [a1]"=&v"(a1_), [a2]"=&v"(a2_), [a3]"=&v"(a3_), [p]"+v"(p_)     \
      : [h]"v"(h_),                                                                     \
        [w0]"v"(wr[0]),  [w1]"v"(wr[1]),  [w2]"v"(wr[2]),  [w3]"v"(wr[3]),              \
        [w4]"v"(wr[4]),  [w5]"v"(wr[5]),  [w6]"v"(wr[6]),  [w7]"v"(wr[7]),              \
        [w8]"v"(wr[8]),  [w9]"v"(wr[9]),  [w10]"v"(wr[10]), [w11]"v"(wr[11]),           \
        [w12]"v"(wr[12]), [w13]"v"(wr[13]), [w14]"v"(wr[14]), [w15]"v"(wr[15]))

__global__ void __launch_bounds__(64, 1)
rnn_fused(const float* __restrict__ x,
          const float* __restrict__ h0,
          const float* __restrict__ Wih,
          const float* __restrict__ Whh,
          const float* __restrict__ bih,
          const float* __restrict__ bhh,
          const float* __restrict__ Wout,
          const float* __restrict__ boutp,
          float* __restrict__ out)
{
    const int lane = (int)threadIdx.x;   // 0..63
    const int j    = lane & 15;          // hidden index this lane owns
    const int g    = lane >> 4;          // 16-lane row group

    // DPP row_ror direction probe (passed rounds 1-2)
    const int pr  = ROTI(j, 0x121);
    const int dir = (__builtin_amdgcn_readfirstlane(pr) == 1) ? 1 : -1;

    float wr[16];                        // shared by all G streams
#pragma unroll
    for (int r = 0; r < 16; ++r)
        wr[r] = Whh[j * HID + ((j + dir * r) & 15)];

    const float wih  = Wih[j];
    const float bias = bih[j] + bhh[j];
    const float wout = Wout[j];
    const float bo   = boutp[0];

    int    b[G];
    float  h[G], p[G], osel[G];
    const float* xb[G];
    float*       ob[G];
#pragma unroll
    for (int s = 0; s < G; ++s) {
        b[s]    = (int)blockIdx.x * 16 + s * 4 + g;
        h[s]    = h0[b[s] * HID + j];
        p[s]    = h[s] * wout;          // reduced inside first step's asm
        osel[s] = 0.0f;
        xb[s]   = x   + (size_t)b[s] * T_LEN;
        ob[s]   = out + (size_t)b[s] * T_LEN;
    }

    float bufA[G][16], bufB[G][16];
#pragma unroll
    for (int s = 0; s < G; ++s)
#pragma unroll
        for (int q = 0; q < 4; ++q) {
            float4 v = *(const float4*)(xb[s] + 4 * q);
            bufA[s][4*q+0] = v.x; bufA[s][4*q+1] = v.y;
            bufA[s][4*q+2] = v.z; bufA[s][4*q+3] = v.w;
        }

    // One 16-step block: prefetch x[t+16..t+31] into nxt, run 16 positions.
    // Per position: 4 independent MATVEC asm blocks back-to-back, then 4
    // independent epilogues (compiler interleaves the latency chains).
    auto body = [&](int t, float (&cur)[G][16], float (&nxt)[G][16]) {
        const int tn = (t + 16) & (T_LEN - 1);      // wraps on last iter (dummy)
#pragma unroll
        for (int s = 0; s < G; ++s)
#pragma unroll
            for (int q = 0; q < 4; ++q) {
                float4 v = *(const float4*)(xb[s] + tn + 4 * q);
                nxt[s][4*q+0] = v.x; nxt[s][4*q+1] = v.y;
                nxt[s][4*q+2] = v.z; nxt[s][4*q+3] = v.w;
            }

#pragma unroll
        for (int pos = 0; pos < 16; ++pos) {
            const int LSEL = (pos + 15) & 15;
            float a0[G], a1[G], a2[G], a3[G];
#pragma unroll
            for (int s = 0; s < G; ++s) {
                a0[s] = fmaf(cur[s][pos], wih, bias);   // xp_t
                MATVEC(a0[s], a1[s], a2[s], a3[s], p[s], h[s]);
            }
#pragma unroll
            for (int s = 0; s < G; ++s) {
                float o = p[s] + bo;                    // out_{t+pos-1}
                osel[s] = (j == LSEL) ? o : osel[s];
                float sum = (a0[s] + a1[s]) + (a2[s] + a3[s]);
                float e   = __builtin_amdgcn_exp2f(sum * 2.8853900817779268f); // e^{2s}
                h[s] = fmaf(-2.0f, __builtin_amdgcn_rcpf(e + 1.0f), 1.0f);     // tanh
                p[s] = h[s] * wout;
            }
            if (pos == 0 && t > 0) {                    // block [t-16..t-1] complete
#pragma unroll
                for (int s = 0; s < G; ++s)
                    ob[s][t - 16 + j] = osel[s];        // coalesced per group
            }
        }
    };

    for (int t = 0; t < T_LEN; t += 32) {               // ping-pong, T/16 is even
        body(t,      bufA, bufB);
        body(t + 16, bufB, bufA);
    }

    // Tail: out[T-1] from the last p; then store final 16-block + hT.
#pragma unroll
    for (int s = 0; s < G; ++s) {
        float q = p[s];
        q += ROTF(q, 0x128);
        q += ROTF(q, 0x124);
        q += ROTF(q, 0x122);
        q += ROTF(q, 0x121);
        float o_last = q + bo;
        osel[s] = (j == 15) ? o_last : osel[s];
        ob[s][T_LEN - 16 + j] = osel[s];
        out[(size_t)BATCH * T_LEN + (size_t)b[s] * HID + j] = h[s];  // hT [1,B,H]
    }
}

extern "C" void kernel_launch(void* const* d_in, const int* in_sizes, int n_in,
                              void* d_out, int out_size, void* d_ws, size_t ws_size,
                              hipStream_t stream)
{
    const float* x    = (const float*)d_in[0];
    const float* h0   = (const float*)d_in[1];
    const float* Wih  = (const float*)d_in[2];
    const float* Whh  = (const float*)d_in[3];
    const float* bih  = (const float*)d_in[4];
    const float* bhh  = (const float*)d_in[5];
    const float* Wout = (const float*)d_in[6];
    const float* bout = (const float*)d_in[7];
    float* out = (float*)d_out;

    rnn_fused<<<dim3(BATCH / 16), dim3(64), 0, stream>>>(
        x, h0, Wih, Whh, bih, bhh, Wout, bout, out);
}

// Round 4
// 1092.925 us; speedup vs baseline: 1.9578x; 1.9578x over previous
//
#include <hip/hip_runtime.h>

// DPP helpers (builtin path: direction probe + final reduce only)
#define ROTI(v, CTRL) __builtin_amdgcn_update_dpp(0, (v), (CTRL), 0xF, 0xF, true)
#define ROTF(x, CTRL) __int_as_float(__builtin_amdgcn_update_dpp(0, __float_as_int(x), (CTRL), 0xF, 0xF, true))

constexpr int T_LEN = 8192;
constexpr int BATCH = 256;
constexpr int HID   = 16;

// Fused step-core (identical schedule to rounds 2/3, both numerically passed):
// 16x16 matvec via v_fmac_f32_dpp/v_mul_f32_dpp on pre-rotated weight rows,
// with the PREVIOUS step's output-projection reduce (v_add_f32_dpp tree)
// interleaved. Hazard discipline: s_nop 1 at head; >=3-inst spacing between
// any write and DPP-read of the same VGPR inside the block.
#define MATVEC(a0_, a1_, a2_, a3_, p_, h_)                                              \
  asm("s_nop 1\n\t"                                                                     \
      "v_fmac_f32 %[a0], %[h], %[w0]\n\t"                                               \
      "v_mul_f32_dpp %[a1], %[h], %[w4] row_ror:4 row_mask:0xf bank_mask:0xf\n\t"       \
      "v_mul_f32_dpp %[a2], %[h], %[w8] row_ror:8 row_mask:0xf bank_mask:0xf\n\t"       \
      "v_mul_f32_dpp %[a3], %[h], %[w12] row_ror:12 row_mask:0xf bank_mask:0xf\n\t"     \
      "v_add_f32_dpp %[p], %[p], %[p] row_ror:8 row_mask:0xf bank_mask:0xf\n\t"         \
      "v_fmac_f32_dpp %[a0], %[h], %[w1] row_ror:1 row_mask:0xf bank_mask:0xf\n\t"      \
      "v_fmac_f32_dpp %[a1], %[h], %[w5] row_ror:5 row_mask:0xf bank_mask:0xf\n\t"      \
      "v_fmac_f32_dpp %[a2], %[h], %[w9] row_ror:9 row_mask:0xf bank_mask:0xf\n\t"      \
      "v_add_f32_dpp %[p], %[p], %[p] row_ror:4 row_mask:0xf bank_mask:0xf\n\t"         \
      "v_fmac_f32_dpp %[a3], %[h], %[w13] row_ror:13 row_mask:0xf bank_mask:0xf\n\t"    \
      "v_fmac_f32_dpp %[a0], %[h], %[w2] row_ror:2 row_mask:0xf bank_mask:0xf\n\t"      \
      "v_fmac_f32_dpp %[a1], %[h], %[w6] row_ror:6 row_mask:0xf bank_mask:0xf\n\t"      \
      "v_add_f32_dpp %[p], %[p], %[p] row_ror:2 row_mask:0xf bank_mask:0xf\n\t"         \
      "v_fmac_f32_dpp %[a2], %[h], %[w10] row_ror:10 row_mask:0xf bank_mask:0xf\n\t"    \
      "v_fmac_f32_dpp %[a3], %[h], %[w14] row_ror:14 row_mask:0xf bank_mask:0xf\n\t"    \
      "v_fmac_f32_dpp %[a0], %[h], %[w3] row_ror:3 row_mask:0xf bank_mask:0xf\n\t"      \
      "v_add_f32_dpp %[p], %[p], %[p] row_ror:1 row_mask:0xf bank_mask:0xf\n\t"         \
      "v_fmac_f32_dpp %[a1], %[h], %[w7] row_ror:7 row_mask:0xf bank_mask:0xf\n\t"      \
      "v_fmac_f32_dpp %[a2], %[h], %[w11] row_ror:11 row_mask:0xf bank_mask:0xf\n\t"    \
      "v_fmac_f32_dpp %[a3], %[h], %[w15] row_ror:15 row_mask:0xf bank_mask:0xf\n\t"    \
      : [a0]"+v"(a0_), [a1]"=&v"(a1_), [a2]"=&v"(a2_), [a3]"=&v"(a3_), [p]"+v"(p_)     \
      : [h]"v"(h_),                                                                     \
        [w0]"v"(wr0),  [w1]"v"(wr1),  [w2]"v"(wr2),  [w3]"v"(wr3),                      \
        [w4]"v"(wr4),  [w5]"v"(wr5),  [w6]"v"(wr6),  [w7]"v"(wr7),                      \
        [w8]"v"(wr8),  [w9]"v"(wr9),  [w10]"v"(wr10), [w11]"v"(wr11),                   \
        [w12]"v"(wr12), [w13]"v"(wr13), [w14]"v"(wr14), [w15]"v"(wr15))

// One position = one step of BOTH streams. All state in named scalars.
// Stream 1's MATVEC issue covers stream 0's tanh-chain latency and vice versa.
#define STEP2(XV0, XV1, LSEL) do {                                                      \
    float a00 = fmaf((XV0), wih, bias), a10, a20, a30;                                  \
    float a01 = fmaf((XV1), wih, bias), a11, a21, a31;                                  \
    MATVEC(a00, a10, a20, a30, p0, hh0);                                                \
    MATVEC(a01, a11, a21, a31, p1, hh1);                                                \
    float o0 = p0 + bo;                                                                 \
    float o1 = p1 + bo;                                                                 \
    osel0 = (j == (LSEL)) ? o0 : osel0;                                                 \
    osel1 = (j == (LSEL)) ? o1 : osel1;                                                 \
    float s0 = (a00 + a10) + (a20 + a30);                                               \
    float s1 = (a01 + a11) + (a21 + a31);                                               \
    float e0 = __builtin_amdgcn_exp2f(s0 * 2.8853900817779268f);                        \
    float e1 = __builtin_amdgcn_exp2f(s1 * 2.8853900817779268f);                        \
    hh0 = fmaf(-2.0f, __builtin_amdgcn_rcpf(e0 + 1.0f), 1.0f);                          \
    hh1 = fmaf(-2.0f, __builtin_amdgcn_rcpf(e1 + 1.0f), 1.0f);                          \
    p0 = hh0 * wout;                                                                    \
    p1 = hh1 * wout;                                                                    \
} while (0)

// 16 positions on buffer set (Q0..Q3 = stream0 x, R0..R3 = stream1 x).
// First STEP2 completes out[tb-1]; the previous 16-block is then stored.
#define BLOCK16(tb, Q0, Q1, Q2, Q3, R0, R1, R2, R3) do {                                \
    STEP2(Q0.x, R0.x, 15);                                                              \
    if ((tb) > 0) { ob0[(tb) - 16 + j] = osel0; ob1[(tb) - 16 + j] = osel1; }           \
    STEP2(Q0.y, R0.y, 0);                                                               \
    STEP2(Q0.z, R0.z, 1);                                                               \
    STEP2(Q0.w, R0.w, 2);                                                               \
    STEP2(Q1.x, R1.x, 3);                                                               \
    STEP2(Q1.y, R1.y, 4);                                                               \
    STEP2(Q1.z, R1.z, 5);                                                               \
    STEP2(Q1.w, R1.w, 6);                                                               \
    STEP2(Q2.x, R2.x, 7);                                                               \
    STEP2(Q2.y, R2.y, 8);                                                               \
    STEP2(Q2.z, R2.z, 9);                                                               \
    STEP2(Q2.w, R2.w, 10);                                                              \
    STEP2(Q3.x, R3.x, 11);                                                              \
    STEP2(Q3.y, R3.y, 12);                                                              \
    STEP2(Q3.z, R3.z, 13);                                                              \
    STEP2(Q3.w, R3.w, 14);                                                              \
} while (0)

__global__ void __launch_bounds__(64, 1)
rnn_fused(const float* __restrict__ x,
          const float* __restrict__ hinit,
          const float* __restrict__ Wih,
          const float* __restrict__ Whh,
          const float* __restrict__ bih,
          const float* __restrict__ bhh,
          const float* __restrict__ Wout,
          const float* __restrict__ boutp,
          float* __restrict__ out)
{
    const int lane = (int)threadIdx.x;   // 0..63
    const int j    = lane & 15;          // hidden index this lane owns
    const int g    = lane >> 4;          // 16-lane row group

    // DPP row_ror direction probe (passed rounds 1-3)
    const int pr  = ROTI(j, 0x121);
    const int dir = (__builtin_amdgcn_readfirstlane(pr) == 1) ? 1 : -1;

    // Pre-rotated W_hh row, named scalars (shared by both streams)
    float wr0  = Whh[j * HID + ((j + dir * 0)  & 15)];
    float wr1  = Whh[j * HID + ((j + dir * 1)  & 15)];
    float wr2  = Whh[j * HID + ((j + dir * 2)  & 15)];
    float wr3  = Whh[j * HID + ((j + dir * 3)  & 15)];
    float wr4  = Whh[j * HID + ((j + dir * 4)  & 15)];
    float wr5  = Whh[j * HID + ((j + dir * 5)  & 15)];
    float wr6  = Whh[j * HID + ((j + dir * 6)  & 15)];
    float wr7  = Whh[j * HID + ((j + dir * 7)  & 15)];
    float wr8  = Whh[j * HID + ((j + dir * 8)  & 15)];
    float wr9  = Whh[j * HID + ((j + dir * 9)  & 15)];
    float wr10 = Whh[j * HID + ((j + dir * 10) & 15)];
    float wr11 = Whh[j * HID + ((j + dir * 11) & 15)];
    float wr12 = Whh[j * HID + ((j + dir * 12) & 15)];
    float wr13 = Whh[j * HID + ((j + dir * 13) & 15)];
    float wr14 = Whh[j * HID + ((j + dir * 14) & 15)];
    float wr15 = Whh[j * HID + ((j + dir * 15) & 15)];

    const float wih  = Wih[j];
    const float bias = bih[j] + bhh[j];
    const float wout = Wout[j];
    const float bo   = boutp[0];

    // Two independent batch streams per lane
    const int b0 = (int)blockIdx.x * 8 + g;        // stream 0
    const int b1 = b0 + 4;                         // stream 1

    float hh0 = hinit[b0 * HID + j];
    float hh1 = hinit[b1 * HID + j];
    float p0 = hh0 * wout;       // reduced inside first step's asm
    float p1 = hh1 * wout;
    float osel0 = 0.0f, osel1 = 0.0f;

    const float* xb0 = x   + (size_t)b0 * T_LEN;
    const float* xb1 = x   + (size_t)b1 * T_LEN;
    float*       ob0 = out + (size_t)b0 * T_LEN;
    float*       ob1 = out + (size_t)b1 * T_LEN;

    // x buffers: ping-pong, all named float4 (NO arrays -> stays in VGPRs)
    float4 A0 = ((const float4*)xb0)[0], A1 = ((const float4*)xb0)[1],
           A2 = ((const float4*)xb0)[2], A3 = ((const float4*)xb0)[3];
    float4 C0 = ((const float4*)xb1)[0], C1 = ((const float4*)xb1)[1],
           C2 = ((const float4*)xb1)[2], C3 = ((const float4*)xb1)[3];
    float4 B0, B1, B2, B3, D0, D1, D2, D3;

    for (int t = 0; t < T_LEN; t += 32) {
        // prefetch block t+16 into B/D while computing block t from A/C
        {
            const float* q0 = xb0 + t + 16;
            const float* q1 = xb1 + t + 16;
            B0 = ((const float4*)q0)[0]; B1 = ((const float4*)q0)[1];
            B2 = ((const float4*)q0)[2]; B3 = ((const float4*)q0)[3];
            D0 = ((const float4*)q1)[0]; D1 = ((const float4*)q1)[1];
            D2 = ((const float4*)q1)[2]; D3 = ((const float4*)q1)[3];
        }
        BLOCK16(t, A0, A1, A2, A3, C0, C1, C2, C3);

        // prefetch block t+32 (wraps harmlessly on last iter) into A/C
        {
            const int tn = (t + 32) & (T_LEN - 1);
            const float* q0 = xb0 + tn;
            const float* q1 = xb1 + tn;
            A0 = ((const float4*)q0)[0]; A1 = ((const float4*)q0)[1];
            A2 = ((const float4*)q0)[2]; A3 = ((const float4*)q0)[3];
            C0 = ((const float4*)q1)[0]; C1 = ((const float4*)q1)[1];
            C2 = ((const float4*)q1)[2]; C3 = ((const float4*)q1)[3];
        }
        BLOCK16(t + 16, B0, B1, B2, B3, D0, D1, D2, D3);
    }

    // Tail: out[T-1] from last p via builtin-DPP reduce; store final block + hT
    {
        float q = p0;
        q += ROTF(q, 0x128); q += ROTF(q, 0x124);
        q += ROTF(q, 0x122); q += ROTF(q, 0x121);
        osel0 = (j == 15) ? (q + bo) : osel0;
        ob0[T_LEN - 16 + j] = osel0;
        out[(size_t)BATCH * T_LEN + (size_t)b0 * HID + j] = hh0;
    }
    {
        float q = p1;
        q += ROTF(q, 0x128); q += ROTF(q, 0x124);
        q += ROTF(q, 0x122); q += ROTF(q, 0x121);
        osel1 = (j == 15) ? (q + bo) : osel1;
        ob1[T_LEN - 16 + j] = osel1;
        out[(size_t)BATCH * T_LEN + (size_t)b1 * HID + j] = hh1;
    }
}

extern "C" void kernel_launch(void* const* d_in, const int* in_sizes, int n_in,
                              void* d_out, int out_size, void* d_ws, size_t ws_size,
                              hipStream_t stream)
{
    const float* x    = (const float*)d_in[0];
    const float* h0   = (const float*)d_in[1];
    const float* Wih  = (const float*)d_in[2];
    const float* Whh  = (const float*)d_in[3];
    const float* bih  = (const float*)d_in[4];
    const float* bhh  = (const float*)d_in[5];
    const float* Wout = (const float*)d_in[6];
    const float* bout = (const float*)d_in[7];
    float* out = (float*)d_out;

    rnn_fused<<<dim3(BATCH / 8), dim3(64), 0, stream>>>(
        x, h0, Wih, Whh, bih, bhh, Wout, bout, out);
}

// Round 5
// 541.704 us; speedup vs baseline: 3.9501x; 2.0176x over previous
//
#include <hip/hip_runtime.h>

// DPP helpers (builtin path: direction probe only)
#define ROTI(v, CTRL) __builtin_amdgcn_update_dpp(0, (v), (CTRL), 0xF, 0xF, true)

constexpr int T_LEN  = 8192;
constexpr int BATCH  = 256;
constexpr int HID    = 16;
constexpr int RING   = 128;   // ring slots (timesteps) in LDS
constexpr int SLOT_W = 68;    // words per slot: 4 batches * 17 (pad vs bank conflicts)
constexpr int CHUNK  = 32;    // producer publish granularity (steps)

// 16x16 matvec of h against pre-rotated (and 2*log2e-pre-scaled) weight rows.
// Same proven schedule as rounds 2-4, minus the p-reduce (offloaded).
// Hazards: s_nop 1 at head covers h written by the immediately preceding
// tanh fma (needs 2 wait states before a DPP read; first DPP read is inst 3).
// a-chains touched every 4 insts (8cy > ~5cy VALU latency).
#define MATVEC(a0_, a1_, a2_, a3_, h_)                                                  \
  asm("s_nop 1\n\t"                                                                     \
      "v_fmac_f32 %[a0], %[h], %[w0]\n\t"                                               \
      "v_mul_f32_dpp %[a1], %[h], %[w4] row_ror:4 row_mask:0xf bank_mask:0xf\n\t"       \
      "v_mul_f32_dpp %[a2], %[h], %[w8] row_ror:8 row_mask:0xf bank_mask:0xf\n\t"       \
      "v_mul_f32_dpp %[a3], %[h], %[w12] row_ror:12 row_mask:0xf bank_mask:0xf\n\t"     \
      "v_fmac_f32_dpp %[a0], %[h], %[w1] row_ror:1 row_mask:0xf bank_mask:0xf\n\t"      \
      "v_fmac_f32_dpp %[a1], %[h], %[w5] row_ror:5 row_mask:0xf bank_mask:0xf\n\t"      \
      "v_fmac_f32_dpp %[a2], %[h], %[w9] row_ror:9 row_mask:0xf bank_mask:0xf\n\t"      \
      "v_fmac_f32_dpp %[a3], %[h], %[w13] row_ror:13 row_mask:0xf bank_mask:0xf\n\t"    \
      "v_fmac_f32_dpp %[a0], %[h], %[w2] row_ror:2 row_mask:0xf bank_mask:0xf\n\t"      \
      "v_fmac_f32_dpp %[a1], %[h], %[w6] row_ror:6 row_mask:0xf bank_mask:0xf\n\t"      \
      "v_fmac_f32_dpp %[a2], %[h], %[w10] row_ror:10 row_mask:0xf bank_mask:0xf\n\t"    \
      "v_fmac_f32_dpp %[a3], %[h], %[w14] row_ror:14 row_mask:0xf bank_mask:0xf\n\t"    \
      "v_fmac_f32_dpp %[a0], %[h], %[w3] row_ror:3 row_mask:0xf bank_mask:0xf\n\t"      \
      "v_fmac_f32_dpp %[a1], %[h], %[w7] row_ror:7 row_mask:0xf bank_mask:0xf\n\t"      \
      "v_fmac_f32_dpp %[a2], %[h], %[w11] row_ror:11 row_mask:0xf bank_mask:0xf\n\t"    \
      "v_fmac_f32_dpp %[a3], %[h], %[w15] row_ror:15 row_mask:0xf bank_mask:0xf\n\t"    \
      : [a0]"+v"(a0_), [a1]"=&v"(a1_), [a2]"=&v"(a2_), [a3]"=&v"(a3_)                  \
      : [h]"v"(h_),                                                                     \
        [w0]"v"(wr0),  [w1]"v"(wr1),  [w2]"v"(wr2),  [w3]"v"(wr3),                      \
        [w4]"v"(wr4),  [w5]"v"(wr5),  [w6]"v"(wr6),  [w7]"v"(wr7),                      \
        [w8]"v"(wr8),  [w9]"v"(wr9),  [w10]"v"(wr10), [w11]"v"(wr11),                   \
        [w12]"v"(wr12), [w13]"v"(wr13), [w14]"v"(wr14), [w15]"v"(wr15))

// One recurrence step: weights pre-scaled by 2*log2(e), so the chain is
// sum -> exp2 -> +1 -> rcp -> fma. h_t goes straight to the LDS ring.
#define STEP(XV) do {                                                                   \
    float a0 = fmaf((XV), wihK, biasK), a1, a2, a3;                                     \
    MATVEC(a0, a1, a2, a3, h);                                                          \
    float s = (a0 + a1) + (a2 + a3);                                                    \
    float e = __builtin_amdgcn_exp2f(s);                                                \
    h = fmaf(-2.0f, __builtin_amdgcn_rcpf(e + 1.0f), 1.0f);                             \
    *rp = h; rp += SLOT_W;                                                              \
} while (0)

#define BLOCK16(C0, C1, C2, C3) do {                                                    \
    STEP(C0.x); STEP(C0.y); STEP(C0.z); STEP(C0.w);                                     \
    STEP(C1.x); STEP(C1.y); STEP(C1.z); STEP(C1.w);                                     \
    STEP(C2.x); STEP(C2.y); STEP(C2.z); STEP(C2.w);                                     \
    STEP(C3.x); STEP(C3.y); STEP(C3.z); STEP(C3.w);                                     \
} while (0)

__global__ void __launch_bounds__(128, 1)
rnn_fused(const float* __restrict__ x,
          const float* __restrict__ hinit,
          const float* __restrict__ Wih,
          const float* __restrict__ Whh,
          const float* __restrict__ bih,
          const float* __restrict__ bhh,
          const float* __restrict__ Wout,
          const float* __restrict__ boutp,
          float* __restrict__ out)
{
    __shared__ float ring[RING * SLOT_W];
    __shared__ int   syncc[2];
    volatile int* prodc = &syncc[0];
    volatile int* consc = &syncc[1];

    const int tid = (int)threadIdx.x;
    if (tid == 0) { syncc[0] = 0; syncc[1] = 0; }
    __syncthreads();

    if (tid < 64) {
        // ---------------- producer wave: the serial recurrence ----------------
        const int j = tid & 15;          // hidden index this lane owns
        const int g = tid >> 4;          // batch sub-index 0..3
        const int b = (int)blockIdx.x * 4 + g;

        // DPP row_ror direction probe (passed rounds 1-4)
        const int pr  = ROTI(j, 0x121);
        const int dir = (__builtin_amdgcn_readfirstlane(pr) == 1) ? 1 : -1;

        const float K2 = 2.8853900817779268f;   // 2*log2(e), folded into weights
        float wr0  = K2 * Whh[j * HID + ((j + dir * 0)  & 15)];
        float wr1  = K2 * Whh[j * HID + ((j + dir * 1)  & 15)];
        float wr2  = K2 * Whh[j * HID + ((j + dir * 2)  & 15)];
        float wr3  = K2 * Whh[j * HID + ((j + dir * 3)  & 15)];
        float wr4  = K2 * Whh[j * HID + ((j + dir * 4)  & 15)];
        float wr5  = K2 * Whh[j * HID + ((j + dir * 5)  & 15)];
        float wr6  = K2 * Whh[j * HID + ((j + dir * 6)  & 15)];
        float wr7  = K2 * Whh[j * HID + ((j + dir * 7)  & 15)];
        float wr8  = K2 * Whh[j * HID + ((j + dir * 8)  & 15)];
        float wr9  = K2 * Whh[j * HID + ((j + dir * 9)  & 15)];
        float wr10 = K2 * Whh[j * HID + ((j + dir * 10) & 15)];
        float wr11 = K2 * Whh[j * HID + ((j + dir * 11) & 15)];
        float wr12 = K2 * Whh[j * HID + ((j + dir * 12) & 15)];
        float wr13 = K2 * Whh[j * HID + ((j + dir * 13) & 15)];
        float wr14 = K2 * Whh[j * HID + ((j + dir * 14) & 15)];
        float wr15 = K2 * Whh[j * HID + ((j + dir * 15) & 15)];

        const float wihK  = K2 * Wih[j];
        const float biasK = K2 * (bih[j] + bhh[j]);

        float h = hinit[b * HID + j];
        const float* xb = x + (size_t)b * T_LEN;

        float4 c0 = ((const float4*)xb)[0], c1 = ((const float4*)xb)[1],
               c2 = ((const float4*)xb)[2], c3 = ((const float4*)xb)[3];

        for (int t0 = 0; t0 < T_LEN; t0 += 16) {
            if ((t0 & (CHUNK - 1)) == 0) {
                // about to write steps [t0, t0+31]; ring holds RING steps
                const int need = t0 + CHUNK - RING;
                if (need > 0) {
                    while (*consc < need) { }
                    __asm__ volatile("" ::: "memory");
                }
            }
            // prefetch next 16 x values (wraps harmlessly on last iter)
            const int tn = (t0 + 16) & (T_LEN - 1);
            const float* q = xb + tn;
            float4 n0 = ((const float4*)q)[0], n1 = ((const float4*)q)[1],
                   n2 = ((const float4*)q)[2], n3 = ((const float4*)q)[3];

            float* rp = &ring[(t0 & (RING - 1)) * SLOT_W + g * 17 + j];
            BLOCK16(c0, c1, c2, c3);
            c0 = n0; c1 = n1; c2 = n2; c3 = n3;

            if (((t0 + 16) & (CHUNK - 1)) == 0) {
                __asm__ volatile("s_waitcnt lgkmcnt(0)" ::: "memory");
                *prodc = t0 + 16;                 // publish completed steps
            }
        }

        // final hidden state hT [1,B,H]
        out[(size_t)BATCH * T_LEN + (size_t)b * HID + j] = h;
    } else {
        // ---------------- consumer wave: output projection + stores ----------------
        const int lane = tid - 64;        // 0..63
        const int tt   = lane & 15;       // timestep offset within chunk
        const int bs   = lane >> 4;       // batch sub-index 0..3
        const int bg   = (int)blockIdx.x * 4 + bs;

        // wout is wave-uniform -> scalar regs
        const float w0  = Wout[0],  w1  = Wout[1],  w2  = Wout[2],  w3  = Wout[3];
        const float w4  = Wout[4],  w5  = Wout[5],  w6  = Wout[6],  w7  = Wout[7];
        const float w8  = Wout[8],  w9  = Wout[9],  w10 = Wout[10], w11 = Wout[11];
        const float w12 = Wout[12], w13 = Wout[13], w14 = Wout[14], w15 = Wout[15];
        const float bo  = boutp[0];

        float* ob = out + (size_t)bg * T_LEN;

        for (int t0 = 0; t0 < T_LEN; t0 += 16) {
            while (*prodc < t0 + 16) { }
            __asm__ volatile("" ::: "memory");

            const float* hr = &ring[((t0 + tt) & (RING - 1)) * SLOT_W + bs * 17];
            float o = bo;
            o = fmaf(hr[0],  w0,  o);
            o = fmaf(hr[1],  w1,  o);
            o = fmaf(hr[2],  w2,  o);
            o = fmaf(hr[3],  w3,  o);
            o = fmaf(hr[4],  w4,  o);
            o = fmaf(hr[5],  w5,  o);
            o = fmaf(hr[6],  w6,  o);
            o = fmaf(hr[7],  w7,  o);
            o = fmaf(hr[8],  w8,  o);
            o = fmaf(hr[9],  w9,  o);
            o = fmaf(hr[10], w10, o);
            o = fmaf(hr[11], w11, o);
            o = fmaf(hr[12], w12, o);
            o = fmaf(hr[13], w13, o);
            o = fmaf(hr[14], w14, o);
            o = fmaf(hr[15], w15, o);
            ob[t0 + tt] = o;                       // coalesced 16-wide per group

            *consc = t0 + 16;                      // release ring slots
        }
    }
}

extern "C" void kernel_launch(void* const* d_in, const int* in_sizes, int n_in,
                              void* d_out, int out_size, void* d_ws, size_t ws_size,
                              hipStream_t stream)
{
    const float* x    = (const float*)d_in[0];
    const float* h0   = (const float*)d_in[1];
    const float* Wih  = (const float*)d_in[2];
    const float* Whh  = (const float*)d_in[3];
    const float* bih  = (const float*)d_in[4];
    const float* bhh  = (const float*)d_in[5];
    const float* Wout = (const float*)d_in[6];
    const float* bout = (const float*)d_in[7];
    float* out = (float*)d_out;

    rnn_fused<<<dim3(BATCH / 4), dim3(128), 0, stream>>>(
        x, h0, Wih, Whh, bih, bhh, Wout, bout, out);
}